// Round 1
// baseline (464.988 us; speedup 1.0000x reference)
//
#include <hip/hip_runtime.h>
#include <stdint.h>

// Problem constants (fixed by the reference)
#define E_EXPERTS 8
#define D_DIM 1024
#define I_DIM 2048
#define T_TOKENS 4096
#define NSLOTS 8192                 // T * K
#define TILE 128
#define MAXPAD (NSLOTS + E_EXPERTS * TILE)   // 9216
#define MAXTILES 72                 // max sum ceil(n_e/128) = 64 + 7

typedef __attribute__((ext_vector_type(8))) short bf16x8;
typedef __attribute__((ext_vector_type(4))) float f32x4;

// ws layout (bytes):
//   0    : cnt[8]
//   64   : cursor[8]
//   128  : ntiles
//   256  : desc[2*MAXTILES] (expert, slot_base)
//   4096 : tok[MAXPAD]     (36864 B)
//   40960: wt[MAXPAD]      (36864 B)
//   131072: xb  [T][D] bf16        ( 8.39 MB)
//   +    : w1t [E][I][D] bf16      (33.55 MB)
//   +    : w2t [E][D][I] bf16      (33.55 MB)
//   +    : h   [MAXPAD][I] bf16    (37.75 MB)   total ~109 MB

__device__ __forceinline__ unsigned short f2b(float f) {
  union { float f; uint32_t u; } v; v.f = f;
  uint32_t r = v.u + 0x7FFFu + ((v.u >> 16) & 1u);   // round-to-nearest-even
  return (unsigned short)(r >> 16);
}

__global__ void convert_x_k(const float* __restrict__ x, unsigned short* __restrict__ xb) {
  int i = (blockIdx.x * blockDim.x + threadIdx.x) * 4;
  float4 v = *(const float4*)(x + i);
  ushort4 o;
  o.x = f2b(v.x); o.y = f2b(v.y); o.z = f2b(v.z); o.w = f2b(v.w);
  *(ushort4*)(xb + i) = o;
}

// src: [E][R][C] fp32  ->  dst: [E][C][R] bf16
__global__ void transpose_cvt_k(const float* __restrict__ src, unsigned short* __restrict__ dst,
                                int R, int C) {
  __shared__ float t[32][33];
  size_t eoff = (size_t)blockIdx.z * R * C;
  int c0 = blockIdx.x * 32, r0 = blockIdx.y * 32;
  int tx = threadIdx.x, ty = threadIdx.y;   // 32 x 8
#pragma unroll
  for (int q = 0; q < 4; q++)
    t[ty + q * 8][tx] = src[eoff + (size_t)(r0 + ty + q * 8) * C + c0 + tx];
  __syncthreads();
#pragma unroll
  for (int q = 0; q < 4; q++)
    dst[eoff + (size_t)(c0 + ty + q * 8) * R + r0 + tx] = f2b(t[tx][ty + q * 8]);
}

__global__ void route_count_k(const int* __restrict__ se, int* __restrict__ cnt) {
  int s = blockIdx.x * blockDim.x + threadIdx.x;
  if (s < NSLOTS) atomicAdd(&cnt[se[s]], 1);
}

__global__ void route_offsets_k(const int* __restrict__ cnt, int* __restrict__ cursor,
                                int* __restrict__ ntiles, int* __restrict__ desc,
                                int* __restrict__ tok, float* __restrict__ wtab) {
  __shared__ int sbase[E_EXPERTS + 1];
  __shared__ int scnt[E_EXPERTS];
  if (threadIdx.x == 0) {
    int acc = 0, nt = 0;
    for (int e = 0; e < E_EXPERTS; e++) {
      int n = cnt[e];
      scnt[e] = n;
      sbase[e] = acc;
      cursor[e] = acc;
      int pad = (n + TILE - 1) & ~(TILE - 1);
      for (int m = 0; m * TILE < pad; m++) { desc[2 * nt] = e; desc[2 * nt + 1] = acc + m * TILE; nt++; }
      acc += pad;
    }
    sbase[E_EXPERTS] = acc;
    *ntiles = nt;
  }
  __syncthreads();
  // fill padded slots with (tok=0, wt=0): exact no-op contributions
  for (int e = 0; e < E_EXPERTS; e++) {
    int s0 = sbase[e] + scnt[e], s1 = sbase[e + 1];
    for (int s = s0 + (int)threadIdx.x; s < s1; s += blockDim.x) { tok[s] = 0; wtab[s] = 0.f; }
  }
}

__global__ void route_scatter_k(const int* __restrict__ se, const float* __restrict__ rw,
                                int* __restrict__ cursor, int* __restrict__ tok,
                                float* __restrict__ wtab) {
  int s = blockIdx.x * blockDim.x + threadIdx.x;
  if (s >= NSLOTS) return;
  int e = se[s];
  int pos = atomicAdd(&cursor[e], 1);
  tok[pos] = s >> 1;          // K=2
  wtab[pos] = rw[s];
}

// 128x128 tile GEMM, BK=64, bf16 MFMA 16x16x32.
// PHASE 1: A = xb gathered via tok[slot]; epilogue silu -> Hout (bf16)
// PHASE 2: A = h rows by slot;            epilogue wt * acc atomicAdd -> Out (fp32)
// Bt is [E][NDIM][KDIM] bf16 (k-contiguous, "B^T" orientation)
template <int KDIM, int NDIM, int PHASE>
__global__ __launch_bounds__(256) void moe_gemm_k(
    const unsigned short* __restrict__ Amat, const unsigned short* __restrict__ Bt,
    const int* __restrict__ desc, const int* __restrict__ ntiles_p,
    const int* __restrict__ tok, const float* __restrict__ wtab,
    unsigned short* __restrict__ Hout, float* __restrict__ Out) {
  int tile = blockIdx.x;
  if (tile >= *ntiles_p) return;
  int e = desc[2 * tile];
  int slot0 = desc[2 * tile + 1];
  int nb = blockIdx.y;

  const unsigned short* Bbase = Bt + (size_t)e * NDIM * KDIM + (size_t)nb * 128 * KDIM;

  __shared__ unsigned short As[128 * 64];
  __shared__ unsigned short Bs[128 * 64];

  int tid = threadIdx.x;
  int lane = tid & 63;
  int wave = tid >> 6;
  int wm = (wave >> 1) * 64, wn = (wave & 1) * 64;
  int l15 = lane & 15, quad = lane >> 4;

  f32x4 acc[4][4] = {};

  int sr = tid >> 3;            // 0..31: row within pass
  int sck = (tid & 7) * 8;      // 0..56: k element offset

  const unsigned short* arow[4];
  const unsigned short* brow[4];
#pragma unroll
  for (int p = 0; p < 4; p++) {
    int r = sr + p * 32;
    int row = (PHASE == 1) ? tok[slot0 + r] : (slot0 + r);
    arow[p] = Amat + (size_t)row * KDIM;
    brow[p] = Bbase + (size_t)r * KDIM;
  }

  for (int kt = 0; kt < KDIM / 64; kt++) {
    int k0 = kt * 64;
#pragma unroll
    for (int p = 0; p < 4; p++) {
      int r = sr + p * 32;
      int cc = (((sck >> 3) ^ (r & 7)) * 8);        // XOR swizzle in 8-elem chunks
      uint4 av = *(const uint4*)(arow[p] + k0 + sck);
      uint4 bv = *(const uint4*)(brow[p] + k0 + sck);
      *(uint4*)&As[r * 64 + cc] = av;
      *(uint4*)&Bs[r * 64 + cc] = bv;
    }
    __syncthreads();
#pragma unroll
    for (int ks = 0; ks < 2; ks++) {
      bf16x8 af[4], bfr[4];
#pragma unroll
      for (int i = 0; i < 4; i++) {
        int r = wm + i * 16 + l15;
        int cc = (((ks * 4 + quad) ^ (r & 7)) * 8);
        af[i] = *(const bf16x8*)&As[r * 64 + cc];
      }
#pragma unroll
      for (int j = 0; j < 4; j++) {
        int r = wn + j * 16 + l15;
        int cc = (((ks * 4 + quad) ^ (r & 7)) * 8);
        bfr[j] = *(const bf16x8*)&Bs[r * 64 + cc];
      }
#pragma unroll
      for (int i = 0; i < 4; i++)
#pragma unroll
        for (int j = 0; j < 4; j++)
          acc[i][j] = __builtin_amdgcn_mfma_f32_16x16x32_bf16(af[i], bfr[j], acc[i][j], 0, 0, 0);
    }
    __syncthreads();
  }

  // Epilogue. C/D frag: col = lane&15, row = quad*4 + reg  [verified m89/m91]
  if (PHASE == 1) {
#pragma unroll
    for (int i = 0; i < 4; i++) {
      int slotr = slot0 + wm + i * 16 + quad * 4;
#pragma unroll
      for (int rg = 0; rg < 4; rg++) {
        int row = slotr + rg;
#pragma unroll
        for (int j = 0; j < 4; j++) {
          int col = nb * 128 + wn + j * 16 + l15;
          float v = acc[i][j][rg];
          float s = v / (1.f + __expf(-v));        // silu
          Hout[(size_t)row * NDIM + col] = f2b(s);
        }
      }
    }
  } else {
#pragma unroll
    for (int i = 0; i < 4; i++) {
      int slotr = slot0 + wm + i * 16 + quad * 4;
#pragma unroll
      for (int rg = 0; rg < 4; rg++) {
        int s = slotr + rg;
        int t = tok[s];
        float w = wtab[s];
#pragma unroll
        for (int j = 0; j < 4; j++) {
          int col = nb * 128 + wn + j * 16 + l15;
          atomicAdd(&Out[(size_t)t * NDIM + col], w * acc[i][j][rg]);
        }
      }
    }
  }
}

extern "C" void kernel_launch(void* const* d_in, const int* in_sizes, int n_in,
                              void* d_out, int out_size, void* d_ws, size_t ws_size,
                              hipStream_t stream) {
  (void)in_sizes; (void)n_in; (void)ws_size;
  const float* x  = (const float*)d_in[0];
  const float* rw = (const float*)d_in[1];
  const int*   se = (const int*)d_in[2];
  const float* w1 = (const float*)d_in[3];
  const float* w2 = (const float*)d_in[4];
  float* out = (float*)d_out;
  char* ws = (char*)d_ws;

  int* cnt    = (int*)(ws + 0);
  int* cursor = (int*)(ws + 64);
  int* ntiles = (int*)(ws + 128);
  int* desc   = (int*)(ws + 256);
  int* tok    = (int*)(ws + 4096);
  float* wtab = (float*)(ws + 40960);
  unsigned short* xb   = (unsigned short*)(ws + 131072);
  unsigned short* w1t  = xb + (size_t)T_TOKENS * D_DIM;
  unsigned short* w2t  = w1t + (size_t)E_EXPERTS * D_DIM * I_DIM;
  unsigned short* hbuf = w2t + (size_t)E_EXPERTS * D_DIM * I_DIM;

  hipMemsetAsync(out, 0, (size_t)out_size * sizeof(float), stream);
  hipMemsetAsync(ws, 0, 1024, stream);

  convert_x_k<<<T_TOKENS * D_DIM / 1024, 256, 0, stream>>>(x, xb);
  transpose_cvt_k<<<dim3(I_DIM / 32, D_DIM / 32, E_EXPERTS), dim3(32, 8), 0, stream>>>(w1, w1t, D_DIM, I_DIM);
  transpose_cvt_k<<<dim3(D_DIM / 32, I_DIM / 32, E_EXPERTS), dim3(32, 8), 0, stream>>>(w2, w2t, I_DIM, D_DIM);
  route_count_k<<<NSLOTS / 256, 256, 0, stream>>>(se, cnt);
  route_offsets_k<<<1, 256, 0, stream>>>(cnt, cursor, ntiles, desc, tok, wtab);
  route_scatter_k<<<NSLOTS / 256, 256, 0, stream>>>(se, rw, cursor, tok, wtab);

  moe_gemm_k<D_DIM, I_DIM, 1><<<dim3(MAXTILES, I_DIM / 128), 256, 0, stream>>>(
      xb, w1t, desc, ntiles, tok, wtab, hbuf, nullptr);
  moe_gemm_k<I_DIM, D_DIM, 2><<<dim3(MAXTILES, D_DIM / 128), 256, 0, stream>>>(
      hbuf, w2t, desc, ntiles, tok, wtab, nullptr, out);
}

// Round 2
// 425.261 us; speedup vs baseline: 1.0934x; 1.0934x over previous
//
#include <hip/hip_runtime.h>
#include <stdint.h>

// Problem constants (fixed by the reference)
#define E_EXPERTS 8
#define D_DIM 1024
#define I_DIM 2048
#define T_TOKENS 4096
#define NSLOTS 8192                 // T * K
#define TILE 128
#define MAXPAD (NSLOTS + E_EXPERTS * TILE)   // 9216
#define MAXTILES 72                 // max sum ceil(n_e/128) = 64 + 7

typedef __attribute__((ext_vector_type(8))) short bf16x8;
typedef __attribute__((ext_vector_type(4))) float f32x4;

__device__ __forceinline__ unsigned short f2b(float f) {
  union { float f; uint32_t u; } v; v.f = f;
  uint32_t r = v.u + 0x7FFFu + ((v.u >> 16) & 1u);   // round-to-nearest-even
  return (unsigned short)(r >> 16);
}

// async 16B global -> LDS (dest = wave-uniform base + lane*16)
__device__ __forceinline__ void async16(const unsigned short* g, unsigned short* l) {
  __builtin_amdgcn_global_load_lds(
      (const __attribute__((address_space(1))) void*)g,
      (__attribute__((address_space(3))) void*)l, 16, 0, 0);
}

__global__ void convert_x_k(const float* __restrict__ x, unsigned short* __restrict__ xb) {
  int i = (blockIdx.x * blockDim.x + threadIdx.x) * 4;
  float4 v = *(const float4*)(x + i);
  ushort4 o;
  o.x = f2b(v.x); o.y = f2b(v.y); o.z = f2b(v.z); o.w = f2b(v.w);
  *(ushort4*)(xb + i) = o;
}

// src: [E][R][C] fp32  ->  dst: [E][C][R] bf16   (vectorized: float4 in, ushort4 out)
__global__ void transpose_cvt_k(const float* __restrict__ src, unsigned short* __restrict__ dst,
                                int R, int C) {
  __shared__ float t[32][33];
  size_t eoff = (size_t)blockIdx.z * R * C;
  int c0 = blockIdx.x * 32, r0 = blockIdx.y * 32;
  int tx = threadIdx.x, ty = threadIdx.y;   // 8 x 32
  float4 v = *(const float4*)(src + eoff + (size_t)(r0 + ty) * C + c0 + tx * 4);
  t[ty][tx * 4 + 0] = v.x; t[ty][tx * 4 + 1] = v.y;
  t[ty][tx * 4 + 2] = v.z; t[ty][tx * 4 + 3] = v.w;
  __syncthreads();
  ushort4 o;
  o.x = f2b(t[tx * 4 + 0][ty]); o.y = f2b(t[tx * 4 + 1][ty]);
  o.z = f2b(t[tx * 4 + 2][ty]); o.w = f2b(t[tx * 4 + 3][ty]);
  *(ushort4*)(dst + eoff + (size_t)(c0 + ty) * R + r0 + tx * 4) = o;
}

__global__ void route_count_k(const int* __restrict__ se, int* __restrict__ cnt) {
  int s = blockIdx.x * blockDim.x + threadIdx.x;
  if (s < NSLOTS) atomicAdd(&cnt[se[s]], 1);
}

__global__ void route_offsets_k(const int* __restrict__ cnt, int* __restrict__ cursor,
                                int* __restrict__ ntiles, int* __restrict__ desc,
                                int* __restrict__ tok, float* __restrict__ wtab) {
  __shared__ int sbase[E_EXPERTS + 1];
  __shared__ int scnt[E_EXPERTS];
  if (threadIdx.x == 0) {
    int acc = 0, nt = 0;
    for (int e = 0; e < E_EXPERTS; e++) {
      int n = cnt[e];
      scnt[e] = n;
      sbase[e] = acc;
      cursor[e] = acc;
      int pad = (n + TILE - 1) & ~(TILE - 1);
      for (int m = 0; m * TILE < pad; m++) { desc[2 * nt] = e; desc[2 * nt + 1] = acc + m * TILE; nt++; }
      acc += pad;
    }
    sbase[E_EXPERTS] = acc;
    *ntiles = nt;
  }
  __syncthreads();
  for (int e = 0; e < E_EXPERTS; e++) {
    int s0 = sbase[e] + scnt[e], s1 = sbase[e + 1];
    for (int s = s0 + (int)threadIdx.x; s < s1; s += blockDim.x) { tok[s] = 0; wtab[s] = 0.f; }
  }
}

__global__ void route_scatter_k(const int* __restrict__ se, const float* __restrict__ rw,
                                int* __restrict__ cursor, int* __restrict__ tok,
                                float* __restrict__ wtab) {
  int s = blockIdx.x * blockDim.x + threadIdx.x;
  if (s >= NSLOTS) return;
  int e = se[s];
  int pos = atomicAdd(&cursor[e], 1);
  tok[pos] = s >> 1;          // K=2
  wtab[pos] = rw[s];
}

// 128x128 tile GEMM, BK=64, bf16 MFMA 16x16x32, global_load_lds width-16 staging.
// LDS layout: slot s=(row<<3|cc) holds global chunk (cc ^ (row&7)) of that row
// (XOR swizzle realized on the LOAD side, since global_load_lds dest is fixed).
template <int KDIM, int NDIM, int PHASE>
__global__ __launch_bounds__(256) void moe_gemm_k(
    const unsigned short* __restrict__ Amat, const unsigned short* __restrict__ Bt,
    const int* __restrict__ desc, const int* __restrict__ ntiles_p,
    const int* __restrict__ tok, const float* __restrict__ wtab,
    unsigned short* __restrict__ Hout, float* __restrict__ Out) {
  int tile = blockIdx.y;
  if (tile >= *ntiles_p) return;
  int e = desc[2 * tile];
  int slot0 = desc[2 * tile + 1];
  int nb = blockIdx.x;

  const unsigned short* Bbase = Bt + (size_t)e * NDIM * KDIM + (size_t)nb * 128 * KDIM;

  __shared__ unsigned short As[128 * 64];
  __shared__ unsigned short Bs[128 * 64];

  int tid = threadIdx.x;
  int lane = tid & 63;
  int wave = tid >> 6;
  int wm = (wave >> 1) * 64, wn = (wave & 1) * 64;
  int l15 = lane & 15, quad = lane >> 4;

  f32x4 acc[4][4] = {};

  int sr = tid >> 3;                               // row base (= wave*8 + lane>>3), 0..31
  int ldoff = (((lane & 7) ^ (lane >> 3)) * 8);    // content-chunk element offset (swizzle inverse)

  const unsigned short* arow[4];
  const unsigned short* brow[4];
#pragma unroll
  for (int p = 0; p < 4; p++) {
    int r = sr + p * 32;
    int row = (PHASE == 1) ? tok[slot0 + r] : (slot0 + r);
    arow[p] = Amat + (size_t)row * KDIM + ldoff;
    brow[p] = Bbase + (size_t)r * KDIM + ldoff;
  }

  for (int kt = 0; kt < KDIM / 64; kt++) {
    int k0 = kt * 64;
#pragma unroll
    for (int p = 0; p < 4; p++) {
      unsigned short* adst = As + (size_t)(p * 256 + wave * 64) * 8;
      unsigned short* bdst = Bs + (size_t)(p * 256 + wave * 64) * 8;
      async16(arow[p] + k0, adst);
      async16(brow[p] + k0, bdst);
    }
    __syncthreads();
#pragma unroll
    for (int ks = 0; ks < 2; ks++) {
      bf16x8 af[4], bfr[4];
#pragma unroll
      for (int i = 0; i < 4; i++) {
        int r = wm + i * 16 + l15;
        int cc = (((ks * 4 + quad) ^ (r & 7)) * 8);
        af[i] = *(const bf16x8*)&As[r * 64 + cc];
      }
#pragma unroll
      for (int j = 0; j < 4; j++) {
        int r = wn + j * 16 + l15;
        int cc = (((ks * 4 + quad) ^ (r & 7)) * 8);
        bfr[j] = *(const bf16x8*)&Bs[r * 64 + cc];
      }
#pragma unroll
      for (int i = 0; i < 4; i++)
#pragma unroll
        for (int j = 0; j < 4; j++)
          acc[i][j] = __builtin_amdgcn_mfma_f32_16x16x32_bf16(af[i], bfr[j], acc[i][j], 0, 0, 0);
    }
    __syncthreads();
  }

  // Epilogue. C/D frag: col = lane&15, row = quad*4 + reg  [verified m89/m91]
  if (PHASE == 1) {
#pragma unroll
    for (int i = 0; i < 4; i++) {
      int slotr = slot0 + wm + i * 16 + quad * 4;
#pragma unroll
      for (int rg = 0; rg < 4; rg++) {
        int row = slotr + rg;
#pragma unroll
        for (int j = 0; j < 4; j++) {
          int col = nb * 128 + wn + j * 16 + l15;
          float v = acc[i][j][rg];
          float s = v / (1.f + __expf(-v));        // silu
          Hout[(size_t)row * NDIM + col] = f2b(s);
        }
      }
    }
  } else {
#pragma unroll
    for (int i = 0; i < 4; i++) {
      int slotr = slot0 + wm + i * 16 + quad * 4;
#pragma unroll
      for (int rg = 0; rg < 4; rg++) {
        int s = slotr + rg;
        int t = tok[s];
        float w = wtab[s];
#pragma unroll
        for (int j = 0; j < 4; j++) {
          int col = nb * 128 + wn + j * 16 + l15;
          atomicAdd(&Out[(size_t)t * NDIM + col], w * acc[i][j][rg]);
        }
      }
    }
  }
}

extern "C" void kernel_launch(void* const* d_in, const int* in_sizes, int n_in,
                              void* d_out, int out_size, void* d_ws, size_t ws_size,
                              hipStream_t stream) {
  (void)in_sizes; (void)n_in; (void)ws_size;
  const float* x  = (const float*)d_in[0];
  const float* rw = (const float*)d_in[1];
  const int*   se = (const int*)d_in[2];
  const float* w1 = (const float*)d_in[3];
  const float* w2 = (const float*)d_in[4];
  float* out = (float*)d_out;
  char* ws = (char*)d_ws;

  int* cnt    = (int*)(ws + 0);
  int* cursor = (int*)(ws + 64);
  int* ntiles = (int*)(ws + 128);
  int* desc   = (int*)(ws + 256);
  int* tok    = (int*)(ws + 4096);
  float* wtab = (float*)(ws + 40960);
  unsigned short* xb   = (unsigned short*)(ws + 131072);
  unsigned short* w1t  = xb + (size_t)T_TOKENS * D_DIM;
  unsigned short* w2t  = w1t + (size_t)E_EXPERTS * D_DIM * I_DIM;
  unsigned short* hbuf = w2t + (size_t)E_EXPERTS * D_DIM * I_DIM;

  hipMemsetAsync(out, 0, (size_t)out_size * sizeof(float), stream);
  hipMemsetAsync(ws, 0, 1024, stream);

  convert_x_k<<<T_TOKENS * D_DIM / 1024, 256, 0, stream>>>(x, xb);
  transpose_cvt_k<<<dim3(I_DIM / 32, D_DIM / 32, E_EXPERTS), dim3(8, 32), 0, stream>>>(w1, w1t, D_DIM, I_DIM);
  transpose_cvt_k<<<dim3(D_DIM / 32, I_DIM / 32, E_EXPERTS), dim3(8, 32), 0, stream>>>(w2, w2t, I_DIM, D_DIM);
  route_count_k<<<NSLOTS / 256, 256, 0, stream>>>(se, cnt);
  route_offsets_k<<<1, 256, 0, stream>>>(cnt, cursor, ntiles, desc, tok, wtab);
  route_scatter_k<<<NSLOTS / 256, 256, 0, stream>>>(se, rw, cursor, tok, wtab);

  moe_gemm_k<D_DIM, I_DIM, 1><<<dim3(I_DIM / 128, MAXTILES), 256, 0, stream>>>(
      xb, w1t, desc, ntiles, tok, wtab, hbuf, nullptr);
  moe_gemm_k<I_DIM, D_DIM, 2><<<dim3(D_DIM / 128, MAXTILES), 256, 0, stream>>>(
      hbuf, w2t, desc, ntiles, tok, wtab, nullptr, out);
}

// Round 3
// 359.243 us; speedup vs baseline: 1.2944x; 1.1838x over previous
//
#include <hip/hip_runtime.h>
#include <stdint.h>

// Problem constants (fixed by the reference)
#define E_EXPERTS 8
#define D_DIM 1024
#define I_DIM 2048
#define T_TOKENS 4096
#define NSLOTS 8192                 // T * K
#define TILE 128
#define MAXPAD (NSLOTS + E_EXPERTS * TILE)   // 9216
#define MAXTILES 72                 // 8 XCDs * 9 tiles; max real tiles = 64..71
#define TPX 9                       // tiles per XCD chunk

typedef __attribute__((ext_vector_type(8))) short bf16x8;
typedef __attribute__((ext_vector_type(4))) float f32x4;

__device__ __forceinline__ unsigned short f2b(float f) {
  union { float f; uint32_t u; } v; v.f = f;
  uint32_t r = v.u + 0x7FFFu + ((v.u >> 16) & 1u);   // round-to-nearest-even
  return (unsigned short)(r >> 16);
}
__device__ __forceinline__ float b2f(unsigned short u) {
  union { uint32_t u; float f; } v; v.u = ((uint32_t)u) << 16; return v.f;
}

// async 16B global -> LDS (dest = wave-uniform base + lane*16)
__device__ __forceinline__ void async16(const unsigned short* g, unsigned short* l) {
  __builtin_amdgcn_global_load_lds(
      (const __attribute__((address_space(1))) void*)g,
      (__attribute__((address_space(3))) void*)l, 16, 0, 0);
}

__global__ void convert_x_k(const float* __restrict__ x, unsigned short* __restrict__ xb) {
  int i = (blockIdx.x * blockDim.x + threadIdx.x) * 4;
  float4 v = *(const float4*)(x + i);
  ushort4 o;
  o.x = f2b(v.x); o.y = f2b(v.y); o.z = f2b(v.z); o.w = f2b(v.w);
  *(ushort4*)(xb + i) = o;
}

// src: [E][R][C] fp32  ->  dst: [E][C][R] bf16   (float4 in, ushort4 out)
__global__ void transpose_cvt_k(const float* __restrict__ src, unsigned short* __restrict__ dst,
                                int R, int C) {
  __shared__ float t[32][33];
  size_t eoff = (size_t)blockIdx.z * R * C;
  int c0 = blockIdx.x * 32, r0 = blockIdx.y * 32;
  int tx = threadIdx.x, ty = threadIdx.y;   // 8 x 32
  float4 v = *(const float4*)(src + eoff + (size_t)(r0 + ty) * C + c0 + tx * 4);
  t[ty][tx * 4 + 0] = v.x; t[ty][tx * 4 + 1] = v.y;
  t[ty][tx * 4 + 2] = v.z; t[ty][tx * 4 + 3] = v.w;
  __syncthreads();
  ushort4 o;
  o.x = f2b(t[tx * 4 + 0][ty]); o.y = f2b(t[tx * 4 + 1][ty]);
  o.z = f2b(t[tx * 4 + 2][ty]); o.w = f2b(t[tx * 4 + 3][ty]);
  *(ushort4*)(dst + eoff + (size_t)(c0 + ty) * R + r0 + tx * 4) = o;
}

__global__ void route_count_k(const int* __restrict__ se, int* __restrict__ cnt) {
  int s = blockIdx.x * blockDim.x + threadIdx.x;
  if (s < NSLOTS) atomicAdd(&cnt[se[s]], 1);
}

__global__ void route_offsets_k(const int* __restrict__ cnt, int* __restrict__ cursor,
                                int* __restrict__ ntiles, int* __restrict__ desc,
                                int* __restrict__ tok) {
  __shared__ int sbase[E_EXPERTS + 1];
  __shared__ int scnt[E_EXPERTS];
  if (threadIdx.x == 0) {
    int acc = 0, nt = 0;
    for (int e = 0; e < E_EXPERTS; e++) {
      int n = cnt[e];
      scnt[e] = n;
      sbase[e] = acc;
      cursor[e] = acc;
      int pad = (n + TILE - 1) & ~(TILE - 1);
      for (int m = 0; m * TILE < pad; m++) { desc[2 * nt] = e; desc[2 * nt + 1] = acc + m * TILE; nt++; }
      acc += pad;
    }
    sbase[E_EXPERTS] = acc;
    *ntiles = nt;
  }
  __syncthreads();
  for (int e = 0; e < E_EXPERTS; e++) {
    int s0 = sbase[e] + scnt[e], s1 = sbase[e + 1];
    for (int s = s0 + (int)threadIdx.x; s < s1; s += blockDim.x) tok[s] = 0;   // pad -> token 0
  }
}

__global__ void route_scatter_k(const int* __restrict__ se, int* __restrict__ cursor,
                                int* __restrict__ tok, int* __restrict__ slot_of) {
  int s = blockIdx.x * blockDim.x + threadIdx.x;
  if (s >= NSLOTS) return;
  int e = se[s];
  int pos = atomicAdd(&cursor[e], 1);
  tok[pos] = s >> 1;          // K=2
  slot_of[s] = pos;
}

// 128x128 tile GEMM, BK=64, bf16 MFMA 16x16x32, global_load_lds width-16 staging.
// 1D grid with XCD-chunked mapping: xcd = id&7 owns tiles [xcd*TPX, xcd*TPX+TPX).
// PHASE 1: A = xb gathered via tok[slot]; silu -> Hout bf16 [slot][NDIM]
// PHASE 2: A = hbuf rows by slot, split-K=2; raw bf16 -> Yout[kh][slot][NDIM]
// B layout [E][NDIM][BSTR] bf16 (k-contiguous); per-block K length = KLEN.
template <int KLEN, int ASTR, int BSTR, int NDIM, int PHASE>
__global__ __launch_bounds__(256) void moe_gemm_k(
    const unsigned short* __restrict__ Amat, const unsigned short* __restrict__ Bt,
    const int* __restrict__ desc, const int* __restrict__ ntiles_p,
    const int* __restrict__ tok, unsigned short* __restrict__ Hout) {
  int id = blockIdx.x;
  int xcd = id & 7, r = id >> 3;
  int ti = xcd * TPX + r % TPX;
  int q = r / TPX;
  int nb, kh;
  if (PHASE == 1) { nb = q; kh = 0; }
  else           { kh = q & 1; nb = q >> 1; }
  if (ti >= *ntiles_p) return;
  int e = desc[2 * ti];
  int slot0 = desc[2 * ti + 1];

  const unsigned short* Bbase = Bt + (size_t)e * NDIM * BSTR + (size_t)nb * 128 * BSTR + kh * KLEN;

  __shared__ unsigned short As[128 * 64];
  __shared__ unsigned short Bs[128 * 64];

  int tid = threadIdx.x;
  int lane = tid & 63;
  int wave = tid >> 6;
  int wm = (wave >> 1) * 64, wn = (wave & 1) * 64;
  int l15 = lane & 15, quad = lane >> 4;

  f32x4 acc[4][4] = {};

  int sr = tid >> 3;                               // row base (= wave*8 + lane>>3), 0..31
  int ldoff = (((lane & 7) ^ (lane >> 3)) * 8);    // content-chunk offset (swizzle inverse)

  const unsigned short* arow[4];
  const unsigned short* brow[4];
#pragma unroll
  for (int p = 0; p < 4; p++) {
    int rr = sr + p * 32;
    int row = (PHASE == 1) ? tok[slot0 + rr] : (slot0 + rr);
    arow[p] = Amat + (size_t)row * ASTR + kh * KLEN + ldoff;
    brow[p] = Bbase + (size_t)rr * BSTR + ldoff;
  }

  for (int kt = 0; kt < KLEN / 64; kt++) {
    int k0 = kt * 64;
#pragma unroll
    for (int p = 0; p < 4; p++) {
      unsigned short* adst = As + (size_t)(p * 256 + wave * 64) * 8;
      unsigned short* bdst = Bs + (size_t)(p * 256 + wave * 64) * 8;
      async16(arow[p] + k0, adst);
      async16(brow[p] + k0, bdst);
    }
    __syncthreads();
#pragma unroll
    for (int ks = 0; ks < 2; ks++) {
      bf16x8 af[4], bfr[4];
#pragma unroll
      for (int i = 0; i < 4; i++) {
        int rr = wm + i * 16 + l15;
        int cc = (((ks * 4 + quad) ^ (rr & 7)) * 8);
        af[i] = *(const bf16x8*)&As[rr * 64 + cc];
      }
#pragma unroll
      for (int j = 0; j < 4; j++) {
        int rr = wn + j * 16 + l15;
        int cc = (((ks * 4 + quad) ^ (rr & 7)) * 8);
        bfr[j] = *(const bf16x8*)&Bs[rr * 64 + cc];
      }
#pragma unroll
      for (int i = 0; i < 4; i++)
#pragma unroll
        for (int j = 0; j < 4; j++)
          acc[i][j] = __builtin_amdgcn_mfma_f32_16x16x32_bf16(af[i], bfr[j], acc[i][j], 0, 0, 0);
    }
    __syncthreads();
  }

  // Epilogue. C/D frag: col = lane&15, row = quad*4 + reg  [verified m89/m91]
#pragma unroll
  for (int i = 0; i < 4; i++) {
    int slotr = slot0 + wm + i * 16 + quad * 4;
#pragma unroll
    for (int rg = 0; rg < 4; rg++) {
      int row = slotr + rg;
      size_t base = (PHASE == 1) ? (size_t)row * NDIM
                                 : ((size_t)kh * MAXPAD + row) * NDIM;
#pragma unroll
      for (int j = 0; j < 4; j++) {
        int col = nb * 128 + wn + j * 16 + l15;
        float v = acc[i][j][rg];
        if (PHASE == 1) v = v / (1.f + __expf(-v));        // silu
        Hout[base + col] = f2b(v);
      }
    }
  }
}

// out[t][d] = sum_k rw[t*2+k] * (y0[slot_of[t*2+k]][d] + y1[slot_of[t*2+k]][d])
__global__ void combine_k(const unsigned short* __restrict__ y, const float* __restrict__ rw,
                          const int* __restrict__ slot_of, float* __restrict__ out) {
  int g = blockIdx.x * blockDim.x + threadIdx.x;   // T*128 threads, 8 elems each
  int t = g >> 7, dd = (g & 127) * 8;
  int s0 = slot_of[2 * t], s1 = slot_of[2 * t + 1];
  float w0 = rw[2 * t], w1 = rw[2 * t + 1];
  const unsigned short* p00 = y + (size_t)s0 * D_DIM + dd;
  const unsigned short* p01 = y + ((size_t)MAXPAD + s0) * D_DIM + dd;
  const unsigned short* p10 = y + (size_t)s1 * D_DIM + dd;
  const unsigned short* p11 = y + ((size_t)MAXPAD + s1) * D_DIM + dd;
  ushort4 a0 = *(const ushort4*)p00, a1 = *(const ushort4*)(p00 + 4);
  ushort4 b0 = *(const ushort4*)p01, b1 = *(const ushort4*)(p01 + 4);
  ushort4 c0 = *(const ushort4*)p10, c1 = *(const ushort4*)(p10 + 4);
  ushort4 d0 = *(const ushort4*)p11, d1 = *(const ushort4*)(p11 + 4);
  float4 o0, o1;
  o0.x = w0 * (b2f(a0.x) + b2f(b0.x)) + w1 * (b2f(c0.x) + b2f(d0.x));
  o0.y = w0 * (b2f(a0.y) + b2f(b0.y)) + w1 * (b2f(c0.y) + b2f(d0.y));
  o0.z = w0 * (b2f(a0.z) + b2f(b0.z)) + w1 * (b2f(c0.z) + b2f(d0.z));
  o0.w = w0 * (b2f(a0.w) + b2f(b0.w)) + w1 * (b2f(c0.w) + b2f(d0.w));
  o1.x = w0 * (b2f(a1.x) + b2f(b1.x)) + w1 * (b2f(c1.x) + b2f(d1.x));
  o1.y = w0 * (b2f(a1.y) + b2f(b1.y)) + w1 * (b2f(c1.y) + b2f(d1.y));
  o1.z = w0 * (b2f(a1.z) + b2f(b1.z)) + w1 * (b2f(c1.z) + b2f(d1.z));
  o1.w = w0 * (b2f(a1.w) + b2f(b1.w)) + w1 * (b2f(c1.w) + b2f(d1.w));
  float* op = out + (size_t)t * D_DIM + dd;
  *(float4*)op = o0;
  *(float4*)(op + 4) = o1;
}

extern "C" void kernel_launch(void* const* d_in, const int* in_sizes, int n_in,
                              void* d_out, int out_size, void* d_ws, size_t ws_size,
                              hipStream_t stream) {
  (void)in_sizes; (void)n_in; (void)ws_size; (void)out_size;
  const float* x  = (const float*)d_in[0];
  const float* rw = (const float*)d_in[1];
  const int*   se = (const int*)d_in[2];
  const float* w1 = (const float*)d_in[3];
  const float* w2 = (const float*)d_in[4];
  float* out = (float*)d_out;
  char* ws = (char*)d_ws;

  // ws layout
  int* cnt     = (int*)(ws + 0);
  int* cursor  = (int*)(ws + 64);
  int* ntiles  = (int*)(ws + 128);
  int* desc    = (int*)(ws + 256);
  int* tok     = (int*)(ws + 4096);          // MAXPAD ints -> ends 40960
  int* slot_of = (int*)(ws + 40960);         // NSLOTS ints -> ends 73728
  unsigned short* xb   = (unsigned short*)(ws + 131072);              // 8.39 MB
  unsigned short* w1t  = xb + (size_t)T_TOKENS * D_DIM;               // 33.55 MB
  unsigned short* w2t  = w1t + (size_t)E_EXPERTS * D_DIM * I_DIM;     // 33.55 MB
  unsigned short* hbuf = w2t + (size_t)E_EXPERTS * D_DIM * I_DIM;     // 37.75 MB
  // ypart overlays xb+w1t (both dead by phase 2): 2 * MAXPAD * D bf16 = 37.75 MB <= 41.94 MB
  unsigned short* ypart = xb;

  hipMemsetAsync(ws, 0, 1024, stream);

  convert_x_k<<<T_TOKENS * D_DIM / 1024, 256, 0, stream>>>(x, xb);
  transpose_cvt_k<<<dim3(I_DIM / 32, D_DIM / 32, E_EXPERTS), dim3(8, 32), 0, stream>>>(w1, w1t, D_DIM, I_DIM);
  transpose_cvt_k<<<dim3(D_DIM / 32, I_DIM / 32, E_EXPERTS), dim3(8, 32), 0, stream>>>(w2, w2t, I_DIM, D_DIM);
  route_count_k<<<NSLOTS / 256, 256, 0, stream>>>(se, cnt);
  route_offsets_k<<<1, 256, 0, stream>>>(cnt, cursor, ntiles, desc, tok);
  route_scatter_k<<<NSLOTS / 256, 256, 0, stream>>>(se, cursor, tok, slot_of);

  // Phase 1: [slots x 1024] @ w1t -> hbuf [slots x 2048];  grid 8*9*16 = 1152
  moe_gemm_k<1024, 1024, 1024, I_DIM, 1><<<8 * TPX * (I_DIM / 128), 256, 0, stream>>>(
      xb, w1t, desc, ntiles, tok, hbuf);
  // Phase 2: [slots x 2048] @ w2t -> ypart, split-K=2;     grid 8*9*(8*2) = 1152
  moe_gemm_k<1024, 2048, 2048, D_DIM, 2><<<8 * TPX * (D_DIM / 128) * 2, 256, 0, stream>>>(
      hbuf, w2t, desc, ntiles, tok, ypart);

  combine_k<<<T_TOKENS * 128 / 256, 256, 0, stream>>>(ypart, rw, slot_of, out);
}

// Round 4
// 290.365 us; speedup vs baseline: 1.6014x; 1.2372x over previous
//
#include <hip/hip_runtime.h>
#include <stdint.h>

// Problem constants (fixed by the reference)
#define E_EXPERTS 8
#define D_DIM 1024
#define I_DIM 2048
#define T_TOKENS 4096
#define NSLOTS 8192                 // T * K
#define TILE 128
#define MAXPAD (NSLOTS + E_EXPERTS * TILE)   // 9216
#define TPX 9                       // tiles per XCD chunk (8*9=72 >= max 71 tiles)

#define W1_TILES (E_EXPERTS * (D_DIM / 32) * (I_DIM / 32))   // 16384
#define W2_TILES W1_TILES                                    // 16384
#define CX_BLOCKS (T_TOKENS * D_DIM / 1024)                  // 4096
#define PREP_GRID (1 + W1_TILES + W2_TILES + CX_BLOCKS)

typedef __attribute__((ext_vector_type(8))) short bf16x8;
typedef __attribute__((ext_vector_type(4))) float f32x4;

__device__ __forceinline__ unsigned short f2b(float f) {
  union { float f; uint32_t u; } v; v.f = f;
  uint32_t r = v.u + 0x7FFFu + ((v.u >> 16) & 1u);   // round-to-nearest-even
  return (unsigned short)(r >> 16);
}
__device__ __forceinline__ float b2f(unsigned short u) {
  union { uint32_t u; float f; } v; v.u = ((uint32_t)u) << 16; return v.f;
}

// async 16B global -> LDS (dest = wave-uniform base + lane*16)
__device__ __forceinline__ void async16(const unsigned short* g, unsigned short* l) {
  __builtin_amdgcn_global_load_lds(
      (const __attribute__((address_space(1))) void*)g,
      (__attribute__((address_space(3))) void*)l, 16, 0, 0);
}

// ---------------- fused prep: routing (block 0) + w1/w2 transpose-cvt + x cvt ----
__global__ __launch_bounds__(256) void prep_k(
    const float* __restrict__ x, const float* __restrict__ w1, const float* __restrict__ w2,
    const int* __restrict__ se,
    unsigned short* __restrict__ xb, unsigned short* __restrict__ w1t,
    unsigned short* __restrict__ w2t,
    int* __restrict__ ntiles, int* __restrict__ desc,
    int* __restrict__ tok, int* __restrict__ slot_of) {
  int b = blockIdx.x;
  int tid = threadIdx.x;

  if (b == 0) {
    // ---- single-workgroup routing: count -> scan -> pad-fill + scatter ----
    __shared__ int scnt[E_EXPERTS], sbase[E_EXPERTS + 1], scur[E_EXPERTS];
    if (tid < E_EXPERTS) scnt[tid] = 0;
    __syncthreads();
    for (int s = tid; s < NSLOTS; s += 256) atomicAdd(&scnt[se[s]], 1);
    __syncthreads();
    if (tid == 0) {
      int acc = 0, nt = 0;
      for (int e = 0; e < E_EXPERTS; e++) {
        int n = scnt[e];
        sbase[e] = acc;
        scur[e] = acc;
        int pad = (n + TILE - 1) & ~(TILE - 1);
        for (int m = 0; m * TILE < pad; m++) { desc[2 * nt] = e; desc[2 * nt + 1] = acc + m * TILE; nt++; }
        acc += pad;
      }
      sbase[E_EXPERTS] = acc;
      *ntiles = nt;
    }
    __syncthreads();
    // pad slots -> token 0 (weight is never read for pads; rows are discarded)
    for (int e = 0; e < E_EXPERTS; e++) {
      int s0 = sbase[e] + scnt[e], s1 = sbase[e + 1];
      for (int s = s0 + tid; s < s1; s += 256) tok[s] = 0;
    }
    // scatter (disjoint from pad range)
    for (int s = tid; s < NSLOTS; s += 256) {
      int e = se[s];
      int pos = atomicAdd(&scur[e], 1);
      tok[pos] = s >> 1;      // K=2
      slot_of[s] = pos;
    }
    return;
  }

  if (b > W1_TILES + W2_TILES) {
    // ---- x fp32 -> bf16 ----
    int cb = b - 1 - W1_TILES - W2_TILES;
    int i = (cb * 256 + tid) * 4;
    float4 v = *(const float4*)(x + i);
    ushort4 o;
    o.x = f2b(v.x); o.y = f2b(v.y); o.z = f2b(v.z); o.w = f2b(v.w);
    *(ushort4*)(xb + i) = o;
    return;
  }

  // ---- 32x32 transpose + cvt: [E][R][C] fp32 -> [E][C][R] bf16 ----
  __shared__ float t[32][33];
  const float* src; unsigned short* dst; int R, C, id;
  if (b <= W1_TILES) { id = b - 1;            src = w1; dst = w1t; R = D_DIM; C = I_DIM; }
  else               { id = b - 1 - W1_TILES; src = w2; dst = w2t; R = I_DIM; C = D_DIM; }
  int eid = id >> 11;                 // 2048 tiles per expert for both matrices
  int tt = id & 2047;
  int ctiles = C / 32;
  int c0 = (tt % ctiles) * 32, r0 = (tt / ctiles) * 32;
  size_t eoff = (size_t)eid * R * C;
  int tx = tid & 7, ty = tid >> 3;    // 8 x 32
  float4 v = *(const float4*)(src + eoff + (size_t)(r0 + ty) * C + c0 + tx * 4);
  t[ty][tx * 4 + 0] = v.x; t[ty][tx * 4 + 1] = v.y;
  t[ty][tx * 4 + 2] = v.z; t[ty][tx * 4 + 3] = v.w;
  __syncthreads();
  ushort4 o;
  o.x = f2b(t[tx * 4 + 0][ty]); o.y = f2b(t[tx * 4 + 1][ty]);
  o.z = f2b(t[tx * 4 + 2][ty]); o.w = f2b(t[tx * 4 + 3][ty]);
  *(ushort4*)(dst + eoff + (size_t)(c0 + ty) * R + r0 + tx * 4) = o;
}

// 128x128 tile GEMM, BK=64, bf16 MFMA 16x16x32, global_load_lds width-16 staging.
// 1D grid, XCD-chunked: xcd = id&7 owns tiles [xcd*TPX, xcd*TPX+TPX).
// PHASE 1: A = xb gathered via tok[slot]; silu -> Hout bf16 [slot][NDIM]
// PHASE 2: A = hbuf rows by slot, split-K=2; raw bf16 -> Yout[kh][slot][NDIM]
template <int KLEN, int ASTR, int BSTR, int NDIM, int PHASE>
__global__ __launch_bounds__(256) void moe_gemm_k(
    const unsigned short* __restrict__ Amat, const unsigned short* __restrict__ Bt,
    const int* __restrict__ desc, const int* __restrict__ ntiles_p,
    const int* __restrict__ tok, unsigned short* __restrict__ Hout) {
  int id = blockIdx.x;
  int xcd = id & 7, r = id >> 3;
  int ti = xcd * TPX + r % TPX;
  int q = r / TPX;
  int nb, kh;
  if (PHASE == 1) { nb = q; kh = 0; }
  else           { kh = q & 1; nb = q >> 1; }
  if (ti >= *ntiles_p) return;
  int e = desc[2 * ti];
  int slot0 = desc[2 * ti + 1];

  const unsigned short* Bbase = Bt + (size_t)e * NDIM * BSTR + (size_t)nb * 128 * BSTR + kh * KLEN;

  __shared__ unsigned short As[128 * 64];
  __shared__ unsigned short Bs[128 * 64];

  int tid = threadIdx.x;
  int lane = tid & 63;
  int wave = tid >> 6;
  int wm = (wave >> 1) * 64, wn = (wave & 1) * 64;
  int l15 = lane & 15, quad = lane >> 4;

  f32x4 acc[4][4] = {};

  int sr = tid >> 3;                               // row base, 0..31
  int ldoff = (((lane & 7) ^ (lane >> 3)) * 8);    // content-chunk offset (swizzle inverse)

  const unsigned short* arow[4];
  const unsigned short* brow[4];
#pragma unroll
  for (int p = 0; p < 4; p++) {
    int rr = sr + p * 32;
    int row = (PHASE == 1) ? tok[slot0 + rr] : (slot0 + rr);
    arow[p] = Amat + (size_t)row * ASTR + kh * KLEN + ldoff;
    brow[p] = Bbase + (size_t)rr * BSTR + ldoff;
  }

  for (int kt = 0; kt < KLEN / 64; kt++) {
    int k0 = kt * 64;
#pragma unroll
    for (int p = 0; p < 4; p++) {
      unsigned short* adst = As + (size_t)(p * 256 + wave * 64) * 8;
      unsigned short* bdst = Bs + (size_t)(p * 256 + wave * 64) * 8;
      async16(arow[p] + k0, adst);
      async16(brow[p] + k0, bdst);
    }
    __syncthreads();
#pragma unroll
    for (int ks = 0; ks < 2; ks++) {
      bf16x8 af[4], bfr[4];
#pragma unroll
      for (int i = 0; i < 4; i++) {
        int rr = wm + i * 16 + l15;
        int cc = (((ks * 4 + quad) ^ (rr & 7)) * 8);
        af[i] = *(const bf16x8*)&As[rr * 64 + cc];
      }
#pragma unroll
      for (int j = 0; j < 4; j++) {
        int rr = wn + j * 16 + l15;
        int cc = (((ks * 4 + quad) ^ (rr & 7)) * 8);
        bfr[j] = *(const bf16x8*)&Bs[rr * 64 + cc];
      }
#pragma unroll
      for (int i = 0; i < 4; i++)
#pragma unroll
        for (int j = 0; j < 4; j++)
          acc[i][j] = __builtin_amdgcn_mfma_f32_16x16x32_bf16(af[i], bfr[j], acc[i][j], 0, 0, 0);
    }
    __syncthreads();
  }

  // Epilogue. C/D frag: col = lane&15, row = quad*4 + reg  [verified m89/m91]
#pragma unroll
  for (int i = 0; i < 4; i++) {
    int slotr = slot0 + wm + i * 16 + quad * 4;
#pragma unroll
    for (int rg = 0; rg < 4; rg++) {
      int row = slotr + rg;
      size_t base = (PHASE == 1) ? (size_t)row * NDIM
                                 : ((size_t)kh * MAXPAD + row) * NDIM;
#pragma unroll
      for (int j = 0; j < 4; j++) {
        int col = nb * 128 + wn + j * 16 + l15;
        float v = acc[i][j][rg];
        if (PHASE == 1) v = v / (1.f + __expf(-v));        // silu
        Hout[base + col] = f2b(v);
      }
    }
  }
}

// out[t][d] = sum_k rw[t*2+k] * (y0[slot_of[t*2+k]][d] + y1[slot_of[t*2+k]][d])
__global__ void combine_k(const unsigned short* __restrict__ y, const float* __restrict__ rw,
                          const int* __restrict__ slot_of, float* __restrict__ out) {
  int g = blockIdx.x * blockDim.x + threadIdx.x;   // T*128 threads, 8 elems each
  int t = g >> 7, dd = (g & 127) * 8;
  int s0 = slot_of[2 * t], s1 = slot_of[2 * t + 1];
  float w0 = rw[2 * t], w1 = rw[2 * t + 1];
  const unsigned short* p00 = y + (size_t)s0 * D_DIM + dd;
  const unsigned short* p01 = y + ((size_t)MAXPAD + s0) * D_DIM + dd;
  const unsigned short* p10 = y + (size_t)s1 * D_DIM + dd;
  const unsigned short* p11 = y + ((size_t)MAXPAD + s1) * D_DIM + dd;
  ushort4 a0 = *(const ushort4*)p00, a1 = *(const ushort4*)(p00 + 4);
  ushort4 b0 = *(const ushort4*)p01, b1 = *(const ushort4*)(p01 + 4);
  ushort4 c0 = *(const ushort4*)p10, c1 = *(const ushort4*)(p10 + 4);
  ushort4 d0 = *(const ushort4*)p11, d1 = *(const ushort4*)(p11 + 4);
  float4 o0, o1;
  o0.x = w0 * (b2f(a0.x) + b2f(b0.x)) + w1 * (b2f(c0.x) + b2f(d0.x));
  o0.y = w0 * (b2f(a0.y) + b2f(b0.y)) + w1 * (b2f(c0.y) + b2f(d0.y));
  o0.z = w0 * (b2f(a0.z) + b2f(b0.z)) + w1 * (b2f(c0.z) + b2f(d0.z));
  o0.w = w0 * (b2f(a0.w) + b2f(b0.w)) + w1 * (b2f(c0.w) + b2f(d0.w));
  o1.x = w0 * (b2f(a1.x) + b2f(b1.x)) + w1 * (b2f(c1.x) + b2f(d1.x));
  o1.y = w0 * (b2f(a1.y) + b2f(b1.y)) + w1 * (b2f(c1.y) + b2f(d1.y));
  o1.z = w0 * (b2f(a1.z) + b2f(b1.z)) + w1 * (b2f(c1.z) + b2f(d1.z));
  o1.w = w0 * (b2f(a1.w) + b2f(b1.w)) + w1 * (b2f(c1.w) + b2f(d1.w));
  float* op = out + (size_t)t * D_DIM + dd;
  *(float4*)op = o0;
  *(float4*)(op + 4) = o1;
}

extern "C" void kernel_launch(void* const* d_in, const int* in_sizes, int n_in,
                              void* d_out, int out_size, void* d_ws, size_t ws_size,
                              hipStream_t stream) {
  (void)in_sizes; (void)n_in; (void)ws_size; (void)out_size;
  const float* x  = (const float*)d_in[0];
  const float* rw = (const float*)d_in[1];
  const int*   se = (const int*)d_in[2];
  const float* w1 = (const float*)d_in[3];
  const float* w2 = (const float*)d_in[4];
  float* out = (float*)d_out;
  char* ws = (char*)d_ws;

  int* ntiles  = (int*)(ws + 128);
  int* desc    = (int*)(ws + 256);
  int* tok     = (int*)(ws + 4096);          // MAXPAD ints -> ends 40960
  int* slot_of = (int*)(ws + 40960);         // NSLOTS ints -> ends 73728
  unsigned short* xb   = (unsigned short*)(ws + 131072);              // 8.39 MB
  unsigned short* w1t  = xb + (size_t)T_TOKENS * D_DIM;               // 33.55 MB
  unsigned short* w2t  = w1t + (size_t)E_EXPERTS * D_DIM * I_DIM;     // 33.55 MB
  unsigned short* hbuf = w2t + (size_t)E_EXPERTS * D_DIM * I_DIM;     // 37.75 MB
  // ypart overlays xb+w1t (both dead after phase 1): 37.75 MB <= 41.94 MB
  unsigned short* ypart = xb;

  prep_k<<<PREP_GRID, 256, 0, stream>>>(x, w1, w2, se, xb, w1t, w2t,
                                        ntiles, desc, tok, slot_of);
  // Phase 1: [slots x 1024] @ w1t -> hbuf [slots x 2048];  grid 1152
  moe_gemm_k<1024, 1024, 1024, I_DIM, 1><<<8 * TPX * (I_DIM / 128), 256, 0, stream>>>(
      xb, w1t, desc, ntiles, tok, hbuf);
  // Phase 2: [slots x 2048] @ w2t -> ypart, split-K=2;     grid 1152
  moe_gemm_k<1024, 2048, 2048, D_DIM, 2><<<8 * TPX * (D_DIM / 128) * 2, 256, 0, stream>>>(
      hbuf, w2t, desc, ntiles, tok, ypart);

  combine_k<<<T_TOKENS * 128 / 256, 256, 0, stream>>>(ypart, rw, slot_of, out);
}